// Round 3
// baseline (546.423 us; speedup 1.0000x reference)
//
#include <hip/hip_runtime.h>

#define NV 100000
#define NE 50000
#define NNZ_C 800000
#define CAP_E 64        // slots per edge   (multiple of 16)
#define CAP_V 48        // slots per vertex (multiple of 8)
#define NB_E 391        // ceil(NE/128)
#define NB_V 782        // ceil(NV/128)
#define CAPB_E 2560     // per-bucket stream cap (Poisson 2048, +11 sigma)
#define CAPB_V 1408     // per-bucket stream cap (Poisson 1024, +12 sigma)
#define OVF_CAP 810000  // overflow covers worst case -> always correct
#define T_ITEMS 2048
#define N_TILES ((NNZ_C + T_ITEMS - 1) / T_ITEMS)   // 391

typedef unsigned int uint32;
typedef unsigned short u16;
typedef u16 u16x8 __attribute__((ext_vector_type(8)));
typedef short short8 __attribute__((ext_vector_type(8)));
typedef float floatx16 __attribute__((ext_vector_type(16)));

__device__ __forceinline__ float bf2f(u16 h) {
  return __uint_as_float(((uint32)h) << 16);
}
__device__ __forceinline__ u16 f2bf(float f) {
  uint32 u = __float_as_uint(f);
  u += 0x7FFF + ((u >> 16) & 1);   // RNE
  return (u16)(u >> 16);
}

// ---------------- zero cursors + dummy gather rows ----------------

__global__ void zero_misc(int* __restrict__ cur, int n,
                          u16* __restrict__ dummyX, u16* __restrict__ dummyXe) {
  int i = blockIdx.x * blockDim.x + threadIdx.x;
  if (i < n) cur[i] = 0;
  if (i < 128) { dummyX[i] = 0; dummyXe[i] = 0; }
}

// ---------------- LDS-binned scatter ----------------

__global__ __launch_bounds__(256) void scatter_binned(const int* __restrict__ vertex,
                                                      const int* __restrict__ edges,
                                                      int* __restrict__ curE,
                                                      int* __restrict__ curV,
                                                      int* __restrict__ ovfCnt,
                                                      uint32* __restrict__ pairE,
                                                      uint32* __restrict__ pairV,
                                                      uint2* __restrict__ ovfE,
                                                      uint2* __restrict__ ovfV) {
  __shared__ int histE[NB_E], baseE[NB_E];
  __shared__ int histV[NB_V], baseV[NB_V];
  int t = threadIdx.x;
  for (int tile = blockIdx.x; tile < N_TILES; tile += gridDim.x) {
    for (int b = t; b < NB_E; b += 256) histE[b] = 0;
    for (int b = t; b < NB_V; b += 256) histV[b] = 0;
    __syncthreads();
    int base = tile * T_ITEMS;
    int ev[8], vv[8], rE[8], rV[8];
    #pragma unroll
    for (int i = 0; i < 8; i++) {
      int k = base + t + i * 256;
      if (k < NNZ_C) {
        ev[i] = edges[k];
        vv[i] = vertex[k];
        rE[i] = atomicAdd(&histE[ev[i] >> 7], 1);
        rV[i] = atomicAdd(&histV[vv[i] >> 7], 1);
      }
    }
    __syncthreads();
    for (int b = t; b < NB_E; b += 256) {
      int h = histE[b];
      baseE[b] = h ? atomicAdd(&curE[b], h) : 0;
    }
    for (int b = t; b < NB_V; b += 256) {
      int h = histV[b];
      baseV[b] = h ? atomicAdd(&curV[b], h) : 0;
    }
    __syncthreads();
    #pragma unroll
    for (int i = 0; i < 8; i++) {
      int k = base + t + i * 256;
      if (k < NNZ_C) {
        uint32 e = (uint32)ev[i], v = (uint32)vv[i];
        uint32 pkE = ((e & 127u) << 25) | v;
        uint32 pkV = ((v & 127u) << 25) | e;
        int pE = baseE[e >> 7] + rE[i];
        if (pE < CAPB_E) pairE[(size_t)(e >> 7) * CAPB_E + pE] = pkE;
        else { int op = atomicAdd(&ovfCnt[0], 1); if (op < OVF_CAP) ovfE[op] = make_uint2(e >> 7, pkE); }
        int pV = baseV[v >> 7] + rV[i];
        if (pV < CAPB_V) pairV[(size_t)(v >> 7) * CAPB_V + pV] = pkV;
        else { int op = atomicAdd(&ovfCnt[1], 1); if (op < OVF_CAP) ovfV[op] = make_uint2(v >> 7, pkV); }
      }
    }
    __syncthreads();
  }
}

// one block per bucket: rank via LDS atomics; pad each key list to multiple of P.
// NOTE: pads at least ONE chunk even when cnt==0, so aggregation kernels may
// load+gather the first chunk unconditionally (dummy rows are zeroed).
__global__ __launch_bounds__(256) void expand(const uint32* __restrict__ pairs,
                                              const int* __restrict__ cur, int capb,
                                              const uint2* __restrict__ ovf,
                                              const int* __restrict__ ovfCnt,
                                              int* __restrict__ items, int cap,
                                              int* __restrict__ cnt, int nKeys,
                                              int P, int dummy) {
  __shared__ int lcnt[128];
  int b = blockIdx.x, t = threadIdx.x;
  if (t < 128) lcnt[t] = 0;
  __syncthreads();
  int n = min(cur[b], capb);
  const uint32* p = pairs + (size_t)b * capb;
  for (int i = t; i < n; i += 256) {
    uint32 w = p[i];
    int loc = w >> 25;
    int val = (int)(w & 0x1FFFFFFu);
    int r = atomicAdd(&lcnt[loc], 1);
    if (r < cap) items[(size_t)((b << 7) + loc) * cap + r] = val;
  }
  int novf = min(*ovfCnt, OVF_CAP);
  for (int i = t; i < novf; i += 256) {
    uint2 w = ovf[i];
    if ((int)w.x == b) {
      int loc = w.y >> 25;
      int val = (int)(w.y & 0x1FFFFFFu);
      int r = atomicAdd(&lcnt[loc], 1);
      if (r < cap) items[(size_t)((b << 7) + loc) * cap + r] = val;
    }
  }
  __syncthreads();
  if (t < 128) {
    int key = (b << 7) + t;
    if (key < nKeys) {
      int c = lcnt[t];
      cnt[key] = c;
      int cc = min(c, cap);
      int padded = min((max(cc, 1) + P - 1) & ~(P - 1), cap);
      for (int r = cc; r < padded; r++)
        items[(size_t)key * cap + r] = dummy;
    }
  }
}

// ---------------- weight prep ----------------
// WT: [0,16384) = W0T[n][k]; then 4x WeffT[i][n][k], Weff=(1-b)I+b*Ws[i]

__global__ void prep_weights(const float* __restrict__ W0, const float* __restrict__ Ws,
                             u16* __restrict__ WT) {
  int idx = blockIdx.x * blockDim.x + threadIdx.x;
  if (idx >= 5 * 16384) return;
  const float betas[4] = {0.4054651081f, 0.2231435513f, 0.1541506798f, 0.1177830357f};
  int sec = idx >> 14;
  int rc = idx & 16383;
  int n = rc >> 7, k = rc & 127;
  float v;
  if (sec == 0) {
    v = W0[k * 128 + n];
  } else {
    int i = sec - 1;
    float b = betas[i];
    v = b * Ws[i * 16384 + k * 128 + n];
    if (k == n) v += 1.0f - b;
  }
  WT[idx] = f2bf(v);
}

// ---------------- edge aggregation (bf16, 16 lanes/row) ----------------
// 16-burst (Poisson-16 edge degree -> one burst covers the common case, max
// memory-level parallelism per wave). Chunk0 items+gathers unconditional
// (expand pads >=16 with dummy -> zero rows); chunk1 prefetched during
// chunk0 gathers. launch_bounds(256,4): 64 data VGPRs live -> cap 128.

__global__ __launch_bounds__(256, 4) void edge_agg(const u16* __restrict__ Xh,
                                                   const int* __restrict__ cntE,
                                                   const int* __restrict__ itemsE,
                                                   u16* __restrict__ Xeh) {
  int g = threadIdx.x >> 4;
  int lane = threadIdx.x & 15;
  int e = blockIdx.x * 16 + g;
  const int* it = itemsE + (size_t)e * CAP_E;
  // chunk-0 items: unconditional (padding guarantees validity)
  int4 i0 = *(const int4*)(it);
  int4 i1 = *(const int4*)(it + 4);
  int4 i2 = *(const int4*)(it + 8);
  int4 i3 = *(const int4*)(it + 12);
  int cnt = cntE[e];            // overlaps with items loads above
  // chunk-0 gathers (dummy rows are zero -> contribute nothing)
  u16x8 r0 = *(const u16x8*)(Xh + (size_t)i0.x * 128 + lane * 8);
  u16x8 r1 = *(const u16x8*)(Xh + (size_t)i0.y * 128 + lane * 8);
  u16x8 r2 = *(const u16x8*)(Xh + (size_t)i0.z * 128 + lane * 8);
  u16x8 r3 = *(const u16x8*)(Xh + (size_t)i0.w * 128 + lane * 8);
  u16x8 r4 = *(const u16x8*)(Xh + (size_t)i1.x * 128 + lane * 8);
  u16x8 r5 = *(const u16x8*)(Xh + (size_t)i1.y * 128 + lane * 8);
  u16x8 r6 = *(const u16x8*)(Xh + (size_t)i1.z * 128 + lane * 8);
  u16x8 r7 = *(const u16x8*)(Xh + (size_t)i1.w * 128 + lane * 8);
  u16x8 r8 = *(const u16x8*)(Xh + (size_t)i2.x * 128 + lane * 8);
  u16x8 r9 = *(const u16x8*)(Xh + (size_t)i2.y * 128 + lane * 8);
  u16x8 rA = *(const u16x8*)(Xh + (size_t)i2.z * 128 + lane * 8);
  u16x8 rB = *(const u16x8*)(Xh + (size_t)i2.w * 128 + lane * 8);
  u16x8 rC = *(const u16x8*)(Xh + (size_t)i3.x * 128 + lane * 8);
  u16x8 rD = *(const u16x8*)(Xh + (size_t)i3.y * 128 + lane * 8);
  u16x8 rE = *(const u16x8*)(Xh + (size_t)i3.z * 128 + lane * 8);
  u16x8 rF = *(const u16x8*)(Xh + (size_t)i3.w * 128 + lane * 8);
  int n16 = (min(cnt, CAP_E) + 15) & ~15;
  // prefetch chunk-1 items while chunk-0 gathers are in flight
  int4 p0, p1, p2, p3;
  if (n16 > 16) {
    p0 = *(const int4*)(it + 16);
    p1 = *(const int4*)(it + 20);
    p2 = *(const int4*)(it + 24);
    p3 = *(const int4*)(it + 28);
  }
  float acc[8];
  #pragma unroll
  for (int q = 0; q < 8; q++) {
    float s0 = (bf2f(r0[q]) + bf2f(r1[q])) + (bf2f(r2[q]) + bf2f(r3[q]));
    float s1 = (bf2f(r4[q]) + bf2f(r5[q])) + (bf2f(r6[q]) + bf2f(r7[q]));
    float s2 = (bf2f(r8[q]) + bf2f(r9[q])) + (bf2f(rA[q]) + bf2f(rB[q]));
    float s3 = (bf2f(rC[q]) + bf2f(rD[q])) + (bf2f(rE[q]) + bf2f(rF[q]));
    acc[q] = (s0 + s1) + (s2 + s3);
  }
  int j = 16;
  while (j < n16) {
    u16x8 s0 = *(const u16x8*)(Xh + (size_t)p0.x * 128 + lane * 8);
    u16x8 s1 = *(const u16x8*)(Xh + (size_t)p0.y * 128 + lane * 8);
    u16x8 s2 = *(const u16x8*)(Xh + (size_t)p0.z * 128 + lane * 8);
    u16x8 s3 = *(const u16x8*)(Xh + (size_t)p0.w * 128 + lane * 8);
    u16x8 s4 = *(const u16x8*)(Xh + (size_t)p1.x * 128 + lane * 8);
    u16x8 s5 = *(const u16x8*)(Xh + (size_t)p1.y * 128 + lane * 8);
    u16x8 s6 = *(const u16x8*)(Xh + (size_t)p1.z * 128 + lane * 8);
    u16x8 s7 = *(const u16x8*)(Xh + (size_t)p1.w * 128 + lane * 8);
    u16x8 s8 = *(const u16x8*)(Xh + (size_t)p2.x * 128 + lane * 8);
    u16x8 s9 = *(const u16x8*)(Xh + (size_t)p2.y * 128 + lane * 8);
    u16x8 sA = *(const u16x8*)(Xh + (size_t)p2.z * 128 + lane * 8);
    u16x8 sB = *(const u16x8*)(Xh + (size_t)p2.w * 128 + lane * 8);
    u16x8 sC = *(const u16x8*)(Xh + (size_t)p3.x * 128 + lane * 8);
    u16x8 sD = *(const u16x8*)(Xh + (size_t)p3.y * 128 + lane * 8);
    u16x8 sE = *(const u16x8*)(Xh + (size_t)p3.z * 128 + lane * 8);
    u16x8 sF = *(const u16x8*)(Xh + (size_t)p3.w * 128 + lane * 8);
    j += 16;
    if (j < n16) {   // rare (degree > 32)
      p0 = *(const int4*)(it + j);
      p1 = *(const int4*)(it + j + 4);
      p2 = *(const int4*)(it + j + 8);
      p3 = *(const int4*)(it + j + 12);
    }
    #pragma unroll
    for (int q = 0; q < 8; q++) {
      float s0x = (bf2f(s0[q]) + bf2f(s1[q])) + (bf2f(s2[q]) + bf2f(s3[q]));
      float s1x = (bf2f(s4[q]) + bf2f(s5[q])) + (bf2f(s6[q]) + bf2f(s7[q]));
      float s2x = (bf2f(s8[q]) + bf2f(s9[q])) + (bf2f(sA[q]) + bf2f(sB[q]));
      float s3x = (bf2f(sC[q]) + bf2f(sD[q])) + (bf2f(sE[q]) + bf2f(sF[q]));
      acc[q] += (s0x + s1x) + (s2x + s3x);
    }
  }
  float inv = 1.f / fmaxf((float)cnt, 1.f);
  u16x8 o;
  #pragma unroll
  for (int q = 0; q < 8; q++) o[q] = f2bf(acc[q] * inv);
  *(u16x8*)(Xeh + (size_t)e * 128 + lane * 8) = o;
}

// ---------------- fused vertex_agg + MFMA GEMM, 64-row tile ----------------
// 64-row tile: lowest-traffic config (R1: 125 MB vs 32-row's 172 MB).
// launch_bounds(256,6): 6 blocks x 17.4 KB = 104 KB LDS, 80 regs/wave
// (48 V + 32 A) <= 85 cap -> 24 waves/CU, matching the grid supply of
// 1563/256 = 6.1 blocks/CU. Gather latency-pipelined as R1.

__global__ __launch_bounds__(256, 6) void gemm_fused(const u16* __restrict__ Xeh,
                                                     const int* __restrict__ cntV,
                                                     const int* __restrict__ itemsV,
                                                     const u16* __restrict__ x0h,
                                                     const u16* __restrict__ WT,
                                                     u16* __restrict__ Yh, int nrows) {
  __shared__ u16 As[64 * 136];
  int t = threadIdx.x;
  int row0 = blockIdx.x * 64;
  int g = t >> 4, lane = t & 15;

  // prologue: all-pass cnt prefetch + pass-0 items chunk0 prefetch
  int vcs[4], cnts[4];
  #pragma unroll
  for (int p = 0; p < 4; p++) {
    int v = row0 + p * 16 + g;
    vcs[p] = min(v, nrows - 1);          // clamp: tail block reads row nrows-1's
    cnts[p] = cntV[vcs[p]];              // list (harmless; output stays zeroed)
  }
  int4 a0 = *(const int4*)(itemsV + (size_t)vcs[0] * CAP_V);
  int4 a1 = *(const int4*)(itemsV + (size_t)vcs[0] * CAP_V + 4);

  #pragma unroll
  for (int pass = 0; pass < 4; pass++) {
    int v = row0 + pass * 16 + g;
    int vc = vcs[pass];
    int cnt = cnts[pass];
    const int* it = itemsV + (size_t)vc * CAP_V;
    // chunk-0 gathers: no dependency on cnt (dummy rows contribute zero)
    u16x8 r0 = *(const u16x8*)(Xeh + (size_t)a0.x * 128 + lane * 8);
    u16x8 r1 = *(const u16x8*)(Xeh + (size_t)a0.y * 128 + lane * 8);
    u16x8 r2 = *(const u16x8*)(Xeh + (size_t)a0.z * 128 + lane * 8);
    u16x8 r3 = *(const u16x8*)(Xeh + (size_t)a0.w * 128 + lane * 8);
    u16x8 r4 = *(const u16x8*)(Xeh + (size_t)a1.x * 128 + lane * 8);
    u16x8 r5 = *(const u16x8*)(Xeh + (size_t)a1.y * 128 + lane * 8);
    u16x8 r6 = *(const u16x8*)(Xeh + (size_t)a1.z * 128 + lane * 8);
    u16x8 r7 = *(const u16x8*)(Xeh + (size_t)a1.w * 128 + lane * 8);
    // x0 row prefetch (used only in epilogue)
    u16x8 x0v = *(const u16x8*)(x0h + (size_t)vc * 128 + lane * 8);
    int n8 = (min(cnt, CAP_V) + 7) & ~7;
    // tail chunk-1 items prefetch, overlapped with chunk-0 gathers
    int4 b0, b1;
    if (n8 > 8) {
      b0 = *(const int4*)(it + 8);
      b1 = *(const int4*)(it + 12);
    }
    // next pass's chunk-0 items prefetch
    if (pass < 3) {
      const int* itn = itemsV + (size_t)vcs[pass + 1] * CAP_V;
      a0 = *(const int4*)(itn);
      a1 = *(const int4*)(itn + 4);
    }
    float acc[8];
    #pragma unroll
    for (int q = 0; q < 8; q++)
      acc[q] = ((bf2f(r0[q]) + bf2f(r1[q])) + (bf2f(r2[q]) + bf2f(r3[q]))) +
               ((bf2f(r4[q]) + bf2f(r5[q])) + (bf2f(r6[q]) + bf2f(r7[q])));
    int j = 8;
    while (j < n8) {
      u16x8 s0 = *(const u16x8*)(Xeh + (size_t)b0.x * 128 + lane * 8);
      u16x8 s1 = *(const u16x8*)(Xeh + (size_t)b0.y * 128 + lane * 8);
      u16x8 s2 = *(const u16x8*)(Xeh + (size_t)b0.z * 128 + lane * 8);
      u16x8 s3 = *(const u16x8*)(Xeh + (size_t)b0.w * 128 + lane * 8);
      u16x8 s4 = *(const u16x8*)(Xeh + (size_t)b1.x * 128 + lane * 8);
      u16x8 s5 = *(const u16x8*)(Xeh + (size_t)b1.y * 128 + lane * 8);
      u16x8 s6 = *(const u16x8*)(Xeh + (size_t)b1.z * 128 + lane * 8);
      u16x8 s7 = *(const u16x8*)(Xeh + (size_t)b1.w * 128 + lane * 8);
      j += 8;
      if (j < n8) {   // degree > 16 (rare)
        b0 = *(const int4*)(it + j);
        b1 = *(const int4*)(it + j + 4);
      }
      #pragma unroll
      for (int q = 0; q < 8; q++)
        acc[q] += ((bf2f(s0[q]) + bf2f(s1[q])) + (bf2f(s2[q]) + bf2f(s3[q]))) +
                  ((bf2f(s4[q]) + bf2f(s5[q])) + (bf2f(s6[q]) + bf2f(s7[q])));
    }
    float inv = 1.f / fmaxf((float)cnt, 1.f);
    float sq = 0.f;
    #pragma unroll
    for (int q = 0; q < 8; q++) { acc[q] *= inv; sq += acc[q] * acc[q]; }
    sq += __shfl_xor(sq, 1, 64);
    sq += __shfl_xor(sq, 2, 64);
    sq += __shfl_xor(sq, 4, 64);
    sq += __shfl_xor(sq, 8, 64);
    float scale = (sq > 0.f) ? rsqrtf(sq) : 0.f;
    u16x8 o = {0, 0, 0, 0, 0, 0, 0, 0};
    if (v < nrows) {
      #pragma unroll
      for (int q = 0; q < 8; q++)
        o[q] = f2bf(0.9f * acc[q] * scale + 0.1f * bf2f(x0v[q]));
    }
    *(u16x8*)&As[(pass * 16 + g) * 136 + lane * 8] = o;
  }
  __syncthreads();

  int w = t >> 6, lane64 = t & 63;
  int l31 = lane64 & 31, kh = lane64 >> 5;
  int wr = w >> 1, wc = w & 1;
  floatx16 acc[2];
  #pragma unroll
  for (int ct = 0; ct < 2; ct++)
    #pragma unroll
    for (int q = 0; q < 16; q++) acc[ct][q] = 0.f;

  const u16* wtb0 = WT + (size_t)(wc * 64 + l31) * 128;
  const u16* wtb1 = WT + (size_t)(wc * 64 + 32 + l31) * 128;
  #pragma unroll
  for (int ks = 0; ks < 8; ks++) {
    int koff = ks * 16 + kh * 8;
    short8 b0 = *(const short8*)(wtb0 + koff);
    short8 b1 = *(const short8*)(wtb1 + koff);
    short8 a0 = *(const short8*)&As[(wr * 32 + l31) * 136 + koff];
    acc[0] = __builtin_amdgcn_mfma_f32_32x32x16_bf16(a0, b0, acc[0], 0, 0, 0);
    acc[1] = __builtin_amdgcn_mfma_f32_32x32x16_bf16(a0, b1, acc[1], 0, 0, 0);
  }
  __syncthreads();

  #pragma unroll
  for (int ct = 0; ct < 2; ct++) {
    int col = wc * 64 + ct * 32 + l31;
    #pragma unroll
    for (int reg = 0; reg < 16; reg++) {
      int row = wr * 32 + (reg & 3) + 8 * (reg >> 2) + 4 * kh;
      As[row * 136 + col] = f2bf(fmaxf(acc[ct][reg], 0.f));
    }
  }
  __syncthreads();
  #pragma unroll
  for (int i = 0; i < 4; i++) {
    int idx = t + 256 * i;
    int r = idx >> 4, c8 = idx & 15;
    if (row0 + r < nrows)
      *(u16x8*)(Yh + (size_t)(row0 + r) * 128 + c8 * 8) =
          *(const u16x8*)&As[r * 136 + c8 * 8];
  }
}

// first GEMM: fp32 A in, +bias, relu, dual bf16 outputs; B from global
__global__ __launch_bounds__(256, 4) void gemm_first(const float* __restrict__ A,
                                                     const u16* __restrict__ WT,
                                                     const float* __restrict__ bias,
                                                     u16* __restrict__ Yh,
                                                     u16* __restrict__ Y2h, int nrows) {
  __shared__ u16 As[128 * 136];
  int t = threadIdx.x;
  int row0 = blockIdx.x * 128;
  #pragma unroll
  for (int i = 0; i < 8; i++) {
    int idx = t + 256 * i;
    int r = idx >> 4, c8 = idx & 15;
    u16x8 v = {0, 0, 0, 0, 0, 0, 0, 0};
    if (row0 + r < nrows) {
      const float* p = A + (size_t)(row0 + r) * 128 + c8 * 8;
      float4 a = *(const float4*)p;
      float4 b = *(const float4*)(p + 4);
      v[0] = f2bf(a.x); v[1] = f2bf(a.y); v[2] = f2bf(a.z); v[3] = f2bf(a.w);
      v[4] = f2bf(b.x); v[5] = f2bf(b.y); v[6] = f2bf(b.z); v[7] = f2bf(b.w);
    }
    *(u16x8*)&As[r * 136 + c8 * 8] = v;
  }
  __syncthreads();

  int w = t >> 6, lane = t & 63;
  int l31 = lane & 31, kh = lane >> 5;
  int wr = w >> 1, wc = w & 1;
  floatx16 acc[2][2];
  #pragma unroll
  for (int rt = 0; rt < 2; rt++)
    #pragma unroll
    for (int ct = 0; ct < 2; ct++)
      #pragma unroll
      for (int q = 0; q < 16; q++) acc[rt][ct][q] = 0.f;

  const u16* wtb0 = WT + (size_t)(wc * 64 + l31) * 128;
  const u16* wtb1 = WT + (size_t)(wc * 64 + 32 + l31) * 128;
  #pragma unroll
  for (int ks = 0; ks < 8; ks++) {
    int koff = ks * 16 + kh * 8;
    short8 b0 = *(const short8*)(wtb0 + koff);
    short8 b1 = *(const short8*)(wtb1 + koff);
    short8 a0 = *(const short8*)&As[(wr * 64 + l31) * 136 + koff];
    short8 a1 = *(const short8*)&As[(wr * 64 + 32 + l31) * 136 + koff];
    acc[0][0] = __builtin_amdgcn_mfma_f32_32x32x16_bf16(a0, b0, acc[0][0], 0, 0, 0);
    acc[0][1] = __builtin_amdgcn_mfma_f32_32x32x16_bf16(a0, b1, acc[0][1], 0, 0, 0);
    acc[1][0] = __builtin_amdgcn_mfma_f32_32x32x16_bf16(a1, b0, acc[1][0], 0, 0, 0);
    acc[1][1] = __builtin_amdgcn_mfma_f32_32x32x16_bf16(a1, b1, acc[1][1], 0, 0, 0);
  }
  __syncthreads();

  #pragma unroll
  for (int rt = 0; rt < 2; rt++)
    #pragma unroll
    for (int ct = 0; ct < 2; ct++) {
      int col = wc * 64 + ct * 32 + l31;
      float bv = bias[col];
      #pragma unroll
      for (int reg = 0; reg < 16; reg++) {
        int row = wr * 64 + rt * 32 + (reg & 3) + 8 * (reg >> 2) + 4 * kh;
        As[row * 136 + col] = f2bf(fmaxf(acc[rt][ct][reg] + bv, 0.f));
      }
    }
  __syncthreads();
  #pragma unroll
  for (int i = 0; i < 8; i++) {
    int idx = t + 256 * i;
    int r = idx >> 4, c8 = idx & 15;
    if (row0 + r < nrows) {
      u16x8 v = *(const u16x8*)&As[r * 136 + c8 * 8];
      *(u16x8*)(Yh + (size_t)(row0 + r) * 128 + c8 * 8) = v;
      *(u16x8*)(Y2h + (size_t)(row0 + r) * 128 + c8 * 8) = v;
    }
  }
}

// ---------------- output GEMM: out[nrows,40] = Xh @ Wout + bout ----------------

__global__ __launch_bounds__(256) void gemm_out(const u16* __restrict__ Xh,
                                                const float* __restrict__ W,
                                                const float* __restrict__ bias,
                                                float* __restrict__ Y, int nrows) {
  __shared__ float xs[128][36];
  __shared__ float ws[32][44];
  int t = threadIdx.x;
  int tr = t >> 3;
  int tc = t & 7;
  int row0 = blockIdx.x * 128;
  float acc[4][5];
  #pragma unroll
  for (int i = 0; i < 4; i++)
    #pragma unroll
    for (int j = 0; j < 5; j++) acc[i][j] = 0.f;

  for (int k0 = 0; k0 < 128; k0 += 32) {
    #pragma unroll
    for (int i = 0; i < 2; i++) {
      int idx = t + 256 * i;
      int r = idx >> 2, c8 = idx & 3;
      int gr = row0 + r;
      u16x8 v = {0, 0, 0, 0, 0, 0, 0, 0};
      if (gr < nrows) v = *(const u16x8*)(Xh + (size_t)gr * 128 + k0 + c8 * 8);
      #pragma unroll
      for (int q = 0; q < 8; q++) xs[r][c8 * 8 + q] = bf2f(v[q]);
    }
    #pragma unroll
    for (int i = 0; i < 5; i++) {
      int idx = t + 256 * i;
      int r = idx / 40, c = idx % 40;
      ws[r][c] = W[(k0 + r) * 40 + c];
    }
    __syncthreads();
    #pragma unroll
    for (int kk4 = 0; kk4 < 8; kk4++) {
      float4 xv[4];
      #pragma unroll
      for (int i = 0; i < 4; i++) xv[i] = *(const float4*)&xs[tr + 32 * i][kk4 * 4];
      #pragma unroll
      for (int q = 0; q < 4; q++) {
        int kk = kk4 * 4 + q;
        float wv[5];
        #pragma unroll
        for (int j = 0; j < 5; j++) wv[j] = ws[kk][tc * 5 + j];
        #pragma unroll
        for (int i = 0; i < 4; i++) {
          float xq = ((const float*)&xv[i])[q];
          #pragma unroll
          for (int j = 0; j < 5; j++) acc[i][j] += xq * wv[j];
        }
      }
    }
    __syncthreads();
  }
  #pragma unroll
  for (int i = 0; i < 4; i++) {
    int gr = row0 + tr + 32 * i;
    if (gr >= nrows) continue;
    #pragma unroll
    for (int j = 0; j < 5; j++) {
      int c = tc * 5 + j;
      Y[(long)gr * 40 + c] = acc[i][j] + bias[c];
    }
  }
}

// ---------------- launch ----------------

extern "C" void kernel_launch(void* const* d_in, const int* in_sizes, int n_in,
                              void* d_out, int out_size, void* d_ws, size_t ws_size,
                              hipStream_t stream) {
  const float* x    = (const float*)d_in[0];
  const float* W0   = (const float*)d_in[1];
  const float* b0   = (const float*)d_in[2];
  const float* Ws   = (const float*)d_in[3];
  const float* Wout = (const float*)d_in[4];
  const float* bout = (const float*)d_in[5];
  const int* vertex = (const int*)d_in[6];
  const int* edges  = (const int*)d_in[7];
  float* out = (float*)d_out;

  char* base = (char*)d_ws;
  size_t o = 0;
  auto alloc = [&](size_t bytes) -> char* {
    char* r = base + o;
    o += (bytes + 255) & ~(size_t)255;
    return r;
  };
  u16* x_curh = (u16*)alloc((size_t)(NV + 1) * 128 * 2);  // +1 dummy zero row
  u16* x0h    = (u16*)alloc((size_t)NV * 128 * 2);
  u16* Xeh    = (u16*)alloc((size_t)(NE + 1) * 128 * 2);  // +1 dummy zero row
  u16* WT     = (u16*)alloc((size_t)5 * 16384 * 2);
  int* cntE   = (int*)alloc((size_t)NE * 4);
  int* cntV   = (int*)alloc((size_t)NV * 4);
  int* itemsE = (int*)alloc((size_t)NE * CAP_E * 4);
  int* itemsV = (int*)alloc((size_t)NV * CAP_V * 4);
  uint32* pairE = (uint32*)alloc((size_t)NB_E * CAPB_E * 4);
  uint32* pairV = (uint32*)alloc((size_t)NB_V * CAPB_V * 4);
  uint2* ovfE  = (uint2*)alloc((size_t)OVF_CAP * 8);
  uint2* ovfV  = (uint2*)alloc((size_t)OVF_CAP * 8);
  int* curAll = (int*)alloc((size_t)(NB_E + NB_V + 2) * 4);  // curE | curV | ovfCnt[2]
  int* curE = curAll;
  int* curV = curAll + NB_E;
  int* ovfCnt = curAll + NB_E + NB_V;

  int nzero = NB_E + NB_V + 2;
  zero_misc<<<(nzero + 255) / 256, 256, 0, stream>>>(curAll, nzero,
                                                     x_curh + (size_t)NV * 128,
                                                     Xeh + (size_t)NE * 128);
  scatter_binned<<<N_TILES, 256, 0, stream>>>(vertex, edges, curE, curV, ovfCnt,
                                              pairE, pairV, ovfE, ovfV);
  expand<<<NB_E, 256, 0, stream>>>(pairE, curE, CAPB_E, ovfE, ovfCnt,
                                   itemsE, CAP_E, cntE, NE, 16, NV);
  expand<<<NB_V, 256, 0, stream>>>(pairV, curV, CAPB_V, ovfV, ovfCnt + 1,
                                   itemsV, CAP_V, cntV, NV, 8, NE);
  prep_weights<<<(5 * 16384 + 255) / 256, 256, 0, stream>>>(W0, Ws, WT);

  int gblocks = (NV + 127) / 128;
  int fblocks = (NV + 63) / 64;
  gemm_first<<<gblocks, 256, 0, stream>>>(x, WT, b0, x_curh, x0h, NV);

  for (int i = 0; i < 4; i++) {
    edge_agg<<<NE / 16, 256, 0, stream>>>(x_curh, cntE, itemsE, Xeh);
    gemm_fused<<<fblocks, 256, 0, stream>>>(Xeh, cntV, itemsV, x0h,
                                            WT + (size_t)(1 + i) * 16384, x_curh, NV);
  }
  gemm_out<<<gblocks, 256, 0, stream>>>(x_curh, Wout, bout, out, NV);
}

// Round 4
// 462.147 us; speedup vs baseline: 1.1824x; 1.1824x over previous
//
#include <hip/hip_runtime.h>

#define NV 100000
#define NE 50000
#define NNZ_C 800000
#define CAP_E 64        // slots per edge   (multiple of 16)
#define CAP_V 48        // slots per vertex (multiple of 8)
#define NB_E 391        // ceil(NE/128)
#define NB_V 782        // ceil(NV/128)
#define CAPB_E 2560     // per-bucket stream cap (Poisson 2048, +11 sigma)
#define CAPB_V 1408     // per-bucket stream cap (Poisson 1024, +12 sigma)
#define OVF_CAP 810000  // overflow covers worst case -> always correct
#define T_ITEMS 2048
#define N_TILES ((NNZ_C + T_ITEMS - 1) / T_ITEMS)   // 391

typedef unsigned int uint32;
typedef unsigned short u16;
typedef u16 u16x8 __attribute__((ext_vector_type(8)));
typedef short short8 __attribute__((ext_vector_type(8)));
typedef float floatx16 __attribute__((ext_vector_type(16)));

__device__ __forceinline__ float bf2f(u16 h) {
  return __uint_as_float(((uint32)h) << 16);
}
__device__ __forceinline__ u16 f2bf(float f) {
  uint32 u = __float_as_uint(f);
  u += 0x7FFF + ((u >> 16) & 1);   // RNE
  return (u16)(u >> 16);
}

// ---------------- zero cursors + dummy gather rows ----------------

__global__ void zero_misc(int* __restrict__ cur, int n,
                          u16* __restrict__ dummyX, u16* __restrict__ dummyXe) {
  int i = blockIdx.x * blockDim.x + threadIdx.x;
  if (i < n) cur[i] = 0;
  if (i < 128) { dummyX[i] = 0; dummyXe[i] = 0; }
}

// ---------------- LDS-binned scatter ----------------

__global__ __launch_bounds__(256) void scatter_binned(const int* __restrict__ vertex,
                                                      const int* __restrict__ edges,
                                                      int* __restrict__ curE,
                                                      int* __restrict__ curV,
                                                      int* __restrict__ ovfCnt,
                                                      uint32* __restrict__ pairE,
                                                      uint32* __restrict__ pairV,
                                                      uint2* __restrict__ ovfE,
                                                      uint2* __restrict__ ovfV) {
  __shared__ int histE[NB_E], baseE[NB_E];
  __shared__ int histV[NB_V], baseV[NB_V];
  int t = threadIdx.x;
  for (int tile = blockIdx.x; tile < N_TILES; tile += gridDim.x) {
    for (int b = t; b < NB_E; b += 256) histE[b] = 0;
    for (int b = t; b < NB_V; b += 256) histV[b] = 0;
    __syncthreads();
    int base = tile * T_ITEMS;
    int ev[8], vv[8], rE[8], rV[8];
    #pragma unroll
    for (int i = 0; i < 8; i++) {
      int k = base + t + i * 256;
      if (k < NNZ_C) {
        ev[i] = edges[k];
        vv[i] = vertex[k];
        rE[i] = atomicAdd(&histE[ev[i] >> 7], 1);
        rV[i] = atomicAdd(&histV[vv[i] >> 7], 1);
      }
    }
    __syncthreads();
    for (int b = t; b < NB_E; b += 256) {
      int h = histE[b];
      baseE[b] = h ? atomicAdd(&curE[b], h) : 0;
    }
    for (int b = t; b < NB_V; b += 256) {
      int h = histV[b];
      baseV[b] = h ? atomicAdd(&curV[b], h) : 0;
    }
    __syncthreads();
    #pragma unroll
    for (int i = 0; i < 8; i++) {
      int k = base + t + i * 256;
      if (k < NNZ_C) {
        uint32 e = (uint32)ev[i], v = (uint32)vv[i];
        uint32 pkE = ((e & 127u) << 25) | v;
        uint32 pkV = ((v & 127u) << 25) | e;
        int pE = baseE[e >> 7] + rE[i];
        if (pE < CAPB_E) pairE[(size_t)(e >> 7) * CAPB_E + pE] = pkE;
        else { int op = atomicAdd(&ovfCnt[0], 1); if (op < OVF_CAP) ovfE[op] = make_uint2(e >> 7, pkE); }
        int pV = baseV[v >> 7] + rV[i];
        if (pV < CAPB_V) pairV[(size_t)(v >> 7) * CAPB_V + pV] = pkV;
        else { int op = atomicAdd(&ovfCnt[1], 1); if (op < OVF_CAP) ovfV[op] = make_uint2(v >> 7, pkV); }
      }
    }
    __syncthreads();
  }
}

// one block per bucket: rank via LDS atomics; pad each key list to multiple of P.
// NOTE: pads at least ONE chunk even when cnt==0, so aggregation kernels may
// load+gather the first chunk unconditionally (dummy rows are zeroed).
__global__ __launch_bounds__(256) void expand(const uint32* __restrict__ pairs,
                                              const int* __restrict__ cur, int capb,
                                              const uint2* __restrict__ ovf,
                                              const int* __restrict__ ovfCnt,
                                              int* __restrict__ items, int cap,
                                              int* __restrict__ cnt, int nKeys,
                                              int P, int dummy) {
  __shared__ int lcnt[128];
  int b = blockIdx.x, t = threadIdx.x;
  if (t < 128) lcnt[t] = 0;
  __syncthreads();
  int n = min(cur[b], capb);
  const uint32* p = pairs + (size_t)b * capb;
  for (int i = t; i < n; i += 256) {
    uint32 w = p[i];
    int loc = w >> 25;
    int val = (int)(w & 0x1FFFFFFu);
    int r = atomicAdd(&lcnt[loc], 1);
    if (r < cap) items[(size_t)((b << 7) + loc) * cap + r] = val;
  }
  int novf = min(*ovfCnt, OVF_CAP);
  for (int i = t; i < novf; i += 256) {
    uint2 w = ovf[i];
    if ((int)w.x == b) {
      int loc = w.y >> 25;
      int val = (int)(w.y & 0x1FFFFFFu);
      int r = atomicAdd(&lcnt[loc], 1);
      if (r < cap) items[(size_t)((b << 7) + loc) * cap + r] = val;
    }
  }
  __syncthreads();
  if (t < 128) {
    int key = (b << 7) + t;
    if (key < nKeys) {
      int c = lcnt[t];
      cnt[key] = c;
      int cc = min(c, cap);
      int padded = min((max(cc, 1) + P - 1) & ~(P - 1), cap);
      for (int r = cc; r < padded; r++)
        items[(size_t)key * cap + r] = dummy;
    }
  }
}

// ---------------- weight prep ----------------
// WT: [0,16384) = W0T[n][k]; then 4x WeffT[i][n][k], Weff=(1-b)I+b*Ws[i]

__global__ void prep_weights(const float* __restrict__ W0, const float* __restrict__ Ws,
                             u16* __restrict__ WT) {
  int idx = blockIdx.x * blockDim.x + threadIdx.x;
  if (idx >= 5 * 16384) return;
  const float betas[4] = {0.4054651081f, 0.2231435513f, 0.1541506798f, 0.1177830357f};
  int sec = idx >> 14;
  int rc = idx & 16383;
  int n = rc >> 7, k = rc & 127;
  float v;
  if (sec == 0) {
    v = W0[k * 128 + n];
  } else {
    int i = sec - 1;
    float b = betas[i];
    v = b * Ws[i * 16384 + k * 128 + n];
    if (k == n) v += 1.0f - b;
  }
  WT[idx] = f2bf(v);
}

// ---------------- edge aggregation (bf16, 16 lanes/row) ----------------
// 16-burst (Poisson-16 edge degree -> one burst covers the common case, max
// memory-level parallelism per wave). Chunk0 items+gathers unconditional
// (expand pads >=16 with dummy -> zero rows); chunk1 prefetched during
// chunk0 gathers. launch_bounds(256,4): generous cap 128 -> no spills.

__global__ __launch_bounds__(256, 4) void edge_agg(const u16* __restrict__ Xh,
                                                   const int* __restrict__ cntE,
                                                   const int* __restrict__ itemsE,
                                                   u16* __restrict__ Xeh) {
  int g = threadIdx.x >> 4;
  int lane = threadIdx.x & 15;
  int e = blockIdx.x * 16 + g;
  const int* it = itemsE + (size_t)e * CAP_E;
  // chunk-0 items: unconditional (padding guarantees validity)
  int4 i0 = *(const int4*)(it);
  int4 i1 = *(const int4*)(it + 4);
  int4 i2 = *(const int4*)(it + 8);
  int4 i3 = *(const int4*)(it + 12);
  int cnt = cntE[e];            // overlaps with items loads above
  // chunk-0 gathers (dummy rows are zero -> contribute nothing)
  u16x8 r0 = *(const u16x8*)(Xh + (size_t)i0.x * 128 + lane * 8);
  u16x8 r1 = *(const u16x8*)(Xh + (size_t)i0.y * 128 + lane * 8);
  u16x8 r2 = *(const u16x8*)(Xh + (size_t)i0.z * 128 + lane * 8);
  u16x8 r3 = *(const u16x8*)(Xh + (size_t)i0.w * 128 + lane * 8);
  u16x8 r4 = *(const u16x8*)(Xh + (size_t)i1.x * 128 + lane * 8);
  u16x8 r5 = *(const u16x8*)(Xh + (size_t)i1.y * 128 + lane * 8);
  u16x8 r6 = *(const u16x8*)(Xh + (size_t)i1.z * 128 + lane * 8);
  u16x8 r7 = *(const u16x8*)(Xh + (size_t)i1.w * 128 + lane * 8);
  u16x8 r8 = *(const u16x8*)(Xh + (size_t)i2.x * 128 + lane * 8);
  u16x8 r9 = *(const u16x8*)(Xh + (size_t)i2.y * 128 + lane * 8);
  u16x8 rA = *(const u16x8*)(Xh + (size_t)i2.z * 128 + lane * 8);
  u16x8 rB = *(const u16x8*)(Xh + (size_t)i2.w * 128 + lane * 8);
  u16x8 rC = *(const u16x8*)(Xh + (size_t)i3.x * 128 + lane * 8);
  u16x8 rD = *(const u16x8*)(Xh + (size_t)i3.y * 128 + lane * 8);
  u16x8 rE = *(const u16x8*)(Xh + (size_t)i3.z * 128 + lane * 8);
  u16x8 rF = *(const u16x8*)(Xh + (size_t)i3.w * 128 + lane * 8);
  int n16 = (min(cnt, CAP_E) + 15) & ~15;
  // prefetch chunk-1 items while chunk-0 gathers are in flight
  int4 p0, p1, p2, p3;
  if (n16 > 16) {
    p0 = *(const int4*)(it + 16);
    p1 = *(const int4*)(it + 20);
    p2 = *(const int4*)(it + 24);
    p3 = *(const int4*)(it + 28);
  }
  float acc[8];
  #pragma unroll
  for (int q = 0; q < 8; q++) {
    float s0 = (bf2f(r0[q]) + bf2f(r1[q])) + (bf2f(r2[q]) + bf2f(r3[q]));
    float s1 = (bf2f(r4[q]) + bf2f(r5[q])) + (bf2f(r6[q]) + bf2f(r7[q]));
    float s2 = (bf2f(r8[q]) + bf2f(r9[q])) + (bf2f(rA[q]) + bf2f(rB[q]));
    float s3 = (bf2f(rC[q]) + bf2f(rD[q])) + (bf2f(rE[q]) + bf2f(rF[q]));
    acc[q] = (s0 + s1) + (s2 + s3);
  }
  int j = 16;
  while (j < n16) {
    u16x8 s0 = *(const u16x8*)(Xh + (size_t)p0.x * 128 + lane * 8);
    u16x8 s1 = *(const u16x8*)(Xh + (size_t)p0.y * 128 + lane * 8);
    u16x8 s2 = *(const u16x8*)(Xh + (size_t)p0.z * 128 + lane * 8);
    u16x8 s3 = *(const u16x8*)(Xh + (size_t)p0.w * 128 + lane * 8);
    u16x8 s4 = *(const u16x8*)(Xh + (size_t)p1.x * 128 + lane * 8);
    u16x8 s5 = *(const u16x8*)(Xh + (size_t)p1.y * 128 + lane * 8);
    u16x8 s6 = *(const u16x8*)(Xh + (size_t)p1.z * 128 + lane * 8);
    u16x8 s7 = *(const u16x8*)(Xh + (size_t)p1.w * 128 + lane * 8);
    u16x8 s8 = *(const u16x8*)(Xh + (size_t)p2.x * 128 + lane * 8);
    u16x8 s9 = *(const u16x8*)(Xh + (size_t)p2.y * 128 + lane * 8);
    u16x8 sA = *(const u16x8*)(Xh + (size_t)p2.z * 128 + lane * 8);
    u16x8 sB = *(const u16x8*)(Xh + (size_t)p2.w * 128 + lane * 8);
    u16x8 sC = *(const u16x8*)(Xh + (size_t)p3.x * 128 + lane * 8);
    u16x8 sD = *(const u16x8*)(Xh + (size_t)p3.y * 128 + lane * 8);
    u16x8 sE = *(const u16x8*)(Xh + (size_t)p3.z * 128 + lane * 8);
    u16x8 sF = *(const u16x8*)(Xh + (size_t)p3.w * 128 + lane * 8);
    j += 16;
    if (j < n16) {   // rare (degree > 32)
      p0 = *(const int4*)(it + j);
      p1 = *(const int4*)(it + j + 4);
      p2 = *(const int4*)(it + j + 8);
      p3 = *(const int4*)(it + j + 12);
    }
    #pragma unroll
    for (int q = 0; q < 8; q++) {
      float s0x = (bf2f(s0[q]) + bf2f(s1[q])) + (bf2f(s2[q]) + bf2f(s3[q]));
      float s1x = (bf2f(s4[q]) + bf2f(s5[q])) + (bf2f(s6[q]) + bf2f(s7[q]));
      float s2x = (bf2f(s8[q]) + bf2f(s9[q])) + (bf2f(sA[q]) + bf2f(sB[q]));
      float s3x = (bf2f(sC[q]) + bf2f(sD[q])) + (bf2f(sE[q]) + bf2f(sF[q]));
      acc[q] += (s0x + s1x) + (s2x + s3x);
    }
  }
  float inv = 1.f / fmaxf((float)cnt, 1.f);
  u16x8 o;
  #pragma unroll
  for (int q = 0; q < 8; q++) o[q] = f2bf(acc[q] * inv);
  *(u16x8*)(Xeh + (size_t)e * 128 + lane * 8) = o;
}

// ---------------- fused vertex_agg + MFMA GEMM, 32-row tile ----------------
// 32-row tile: grid 3125 = 12.2 blocks/CU SUPPLY (deep refill pool vs the
// 64-tile's 6.1 -> tail/imbalance starved CUs). launch_bounds(256,5): cap 102
// -> compiler uses its natural ~70-85 regs, NO spills (the (256,6) rounds
// spilled ~20 dwords/thread: WRITE_SIZE 25->53/60 MB; that was the regression).
// Gather: 16 groups x 2 passes; chunk0 unconditional; items prefetched.
// MFMA: 4 waves, each 32 rows x 32 cols.

__global__ __launch_bounds__(256, 5) void gemm_fused(const u16* __restrict__ Xeh,
                                                     const int* __restrict__ cntV,
                                                     const int* __restrict__ itemsV,
                                                     const u16* __restrict__ x0h,
                                                     const u16* __restrict__ WT,
                                                     u16* __restrict__ Yh, int nrows) {
  __shared__ u16 As[32 * 136];
  int t = threadIdx.x;
  int row0 = blockIdx.x * 32;
  int g = t >> 4, lane = t & 15;

  // prologue: all-pass cnt prefetch + pass-0 items chunk0 prefetch
  int vcs[2], cnts[2];
  #pragma unroll
  for (int p = 0; p < 2; p++) {
    int v = row0 + p * 16 + g;
    vcs[p] = min(v, nrows - 1);          // clamp (NV%32==0 so never taken; safe)
    cnts[p] = cntV[vcs[p]];
  }
  int4 a0 = *(const int4*)(itemsV + (size_t)vcs[0] * CAP_V);
  int4 a1 = *(const int4*)(itemsV + (size_t)vcs[0] * CAP_V + 4);

  #pragma unroll
  for (int pass = 0; pass < 2; pass++) {
    int v = row0 + pass * 16 + g;
    int vc = vcs[pass];
    int cnt = cnts[pass];
    const int* it = itemsV + (size_t)vc * CAP_V;
    // chunk-0 gathers: no dependency on cnt (dummy rows contribute zero)
    u16x8 r0 = *(const u16x8*)(Xeh + (size_t)a0.x * 128 + lane * 8);
    u16x8 r1 = *(const u16x8*)(Xeh + (size_t)a0.y * 128 + lane * 8);
    u16x8 r2 = *(const u16x8*)(Xeh + (size_t)a0.z * 128 + lane * 8);
    u16x8 r3 = *(const u16x8*)(Xeh + (size_t)a0.w * 128 + lane * 8);
    u16x8 r4 = *(const u16x8*)(Xeh + (size_t)a1.x * 128 + lane * 8);
    u16x8 r5 = *(const u16x8*)(Xeh + (size_t)a1.y * 128 + lane * 8);
    u16x8 r6 = *(const u16x8*)(Xeh + (size_t)a1.z * 128 + lane * 8);
    u16x8 r7 = *(const u16x8*)(Xeh + (size_t)a1.w * 128 + lane * 8);
    // x0 row prefetch (used only in epilogue)
    u16x8 x0v = *(const u16x8*)(x0h + (size_t)vc * 128 + lane * 8);
    int n8 = (min(cnt, CAP_V) + 7) & ~7;
    // tail chunk-1 items prefetch, overlapped with chunk-0 gathers
    int4 b0, b1;
    if (n8 > 8) {
      b0 = *(const int4*)(it + 8);
      b1 = *(const int4*)(it + 12);
    }
    // next pass's chunk-0 items prefetch
    if (pass < 1) {
      const int* itn = itemsV + (size_t)vcs[pass + 1] * CAP_V;
      a0 = *(const int4*)(itn);
      a1 = *(const int4*)(itn + 4);
    }
    float acc[8];
    #pragma unroll
    for (int q = 0; q < 8; q++)
      acc[q] = ((bf2f(r0[q]) + bf2f(r1[q])) + (bf2f(r2[q]) + bf2f(r3[q]))) +
               ((bf2f(r4[q]) + bf2f(r5[q])) + (bf2f(r6[q]) + bf2f(r7[q])));
    int j = 8;
    while (j < n8) {
      u16x8 s0 = *(const u16x8*)(Xeh + (size_t)b0.x * 128 + lane * 8);
      u16x8 s1 = *(const u16x8*)(Xeh + (size_t)b0.y * 128 + lane * 8);
      u16x8 s2 = *(const u16x8*)(Xeh + (size_t)b0.z * 128 + lane * 8);
      u16x8 s3 = *(const u16x8*)(Xeh + (size_t)b0.w * 128 + lane * 8);
      u16x8 s4 = *(const u16x8*)(Xeh + (size_t)b1.x * 128 + lane * 8);
      u16x8 s5 = *(const u16x8*)(Xeh + (size_t)b1.y * 128 + lane * 8);
      u16x8 s6 = *(const u16x8*)(Xeh + (size_t)b1.z * 128 + lane * 8);
      u16x8 s7 = *(const u16x8*)(Xeh + (size_t)b1.w * 128 + lane * 8);
      j += 8;
      if (j < n8) {
        b0 = *(const int4*)(it + j);
        b1 = *(const int4*)(it + j + 4);
      }
      #pragma unroll
      for (int q = 0; q < 8; q++)
        acc[q] += ((bf2f(s0[q]) + bf2f(s1[q])) + (bf2f(s2[q]) + bf2f(s3[q]))) +
                  ((bf2f(s4[q]) + bf2f(s5[q])) + (bf2f(s6[q]) + bf2f(s7[q])));
    }
    float inv = 1.f / fmaxf((float)cnt, 1.f);
    float sq = 0.f;
    #pragma unroll
    for (int q = 0; q < 8; q++) { acc[q] *= inv; sq += acc[q] * acc[q]; }
    sq += __shfl_xor(sq, 1, 64);
    sq += __shfl_xor(sq, 2, 64);
    sq += __shfl_xor(sq, 4, 64);
    sq += __shfl_xor(sq, 8, 64);
    float scale = (sq > 0.f) ? rsqrtf(sq) : 0.f;
    u16x8 o = {0, 0, 0, 0, 0, 0, 0, 0};
    if (v < nrows) {
      #pragma unroll
      for (int q = 0; q < 8; q++)
        o[q] = f2bf(0.9f * acc[q] * scale + 0.1f * bf2f(x0v[q]));
    }
    *(u16x8*)&As[(pass * 16 + g) * 136 + lane * 8] = o;
  }
  __syncthreads();

  // MFMA: 4 waves, wave w computes rows 0..31 x cols [w*32, w*32+32)
  int w = t >> 6, lane64 = t & 63;
  int l31 = lane64 & 31, kh = lane64 >> 5;
  floatx16 acc;
  #pragma unroll
  for (int q = 0; q < 16; q++) acc[q] = 0.f;

  const u16* wtb = WT + (size_t)(w * 32 + l31) * 128;
  #pragma unroll
  for (int ks = 0; ks < 8; ks++) {
    int koff = ks * 16 + kh * 8;
    short8 b0 = *(const short8*)(wtb + koff);
    short8 a0 = *(const short8*)&As[l31 * 136 + koff];
    acc = __builtin_amdgcn_mfma_f32_32x32x16_bf16(a0, b0, acc, 0, 0, 0);
  }
  __syncthreads();

  int col = w * 32 + l31;
  #pragma unroll
  for (int reg = 0; reg < 16; reg++) {
    int row = (reg & 3) + 8 * (reg >> 2) + 4 * kh;
    As[row * 136 + col] = f2bf(fmaxf(acc[reg], 0.f));
  }
  __syncthreads();
  #pragma unroll
  for (int i = 0; i < 2; i++) {
    int idx = t + 256 * i;
    int r = idx >> 4, c8 = idx & 15;
    if (row0 + r < nrows)
      *(u16x8*)(Yh + (size_t)(row0 + r) * 128 + c8 * 8) =
          *(const u16x8*)&As[r * 136 + c8 * 8];
  }
}

// first GEMM: fp32 A in, +bias, relu, dual bf16 outputs; B from global
__global__ __launch_bounds__(256, 4) void gemm_first(const float* __restrict__ A,
                                                     const u16* __restrict__ WT,
                                                     const float* __restrict__ bias,
                                                     u16* __restrict__ Yh,
                                                     u16* __restrict__ Y2h, int nrows) {
  __shared__ u16 As[128 * 136];
  int t = threadIdx.x;
  int row0 = blockIdx.x * 128;
  #pragma unroll
  for (int i = 0; i < 8; i++) {
    int idx = t + 256 * i;
    int r = idx >> 4, c8 = idx & 15;
    u16x8 v = {0, 0, 0, 0, 0, 0, 0, 0};
    if (row0 + r < nrows) {
      const float* p = A + (size_t)(row0 + r) * 128 + c8 * 8;
      float4 a = *(const float4*)p;
      float4 b = *(const float4*)(p + 4);
      v[0] = f2bf(a.x); v[1] = f2bf(a.y); v[2] = f2bf(a.z); v[3] = f2bf(a.w);
      v[4] = f2bf(b.x); v[5] = f2bf(b.y); v[6] = f2bf(b.z); v[7] = f2bf(b.w);
    }
    *(u16x8*)&As[r * 136 + c8 * 8] = v;
  }
  __syncthreads();

  int w = t >> 6, lane = t & 63;
  int l31 = lane & 31, kh = lane >> 5;
  int wr = w >> 1, wc = w & 1;
  floatx16 acc[2][2];
  #pragma unroll
  for (int rt = 0; rt < 2; rt++)
    #pragma unroll
    for (int ct = 0; ct < 2; ct++)
      #pragma unroll
      for (int q = 0; q < 16; q++) acc[rt][ct][q] = 0.f;

  const u16* wtb0 = WT + (size_t)(wc * 64 + l31) * 128;
  const u16* wtb1 = WT + (size_t)(wc * 64 + 32 + l31) * 128;
  #pragma unroll
  for (int ks = 0; ks < 8; ks++) {
    int koff = ks * 16 + kh * 8;
    short8 b0 = *(const short8*)(wtb0 + koff);
    short8 b1 = *(const short8*)(wtb1 + koff);
    short8 a0 = *(const short8*)&As[(wr * 64 + l31) * 136 + koff];
    short8 a1 = *(const short8*)&As[(wr * 64 + 32 + l31) * 136 + koff];
    acc[0][0] = __builtin_amdgcn_mfma_f32_32x32x16_bf16(a0, b0, acc[0][0], 0, 0, 0);
    acc[0][1] = __builtin_amdgcn_mfma_f32_32x32x16_bf16(a0, b1, acc[0][1], 0, 0, 0);
    acc[1][0] = __builtin_amdgcn_mfma_f32_32x32x16_bf16(a1, b0, acc[1][0], 0, 0, 0);
    acc[1][1] = __builtin_amdgcn_mfma_f32_32x32x16_bf16(a1, b1, acc[1][1], 0, 0, 0);
  }
  __syncthreads();

  #pragma unroll
  for (int rt = 0; rt < 2; rt++)
    #pragma unroll
    for (int ct = 0; ct < 2; ct++) {
      int col = wc * 64 + ct * 32 + l31;
      float bv = bias[col];
      #pragma unroll
      for (int reg = 0; reg < 16; reg++) {
        int row = wr * 64 + rt * 32 + (reg & 3) + 8 * (reg >> 2) + 4 * kh;
        As[row * 136 + col] = f2bf(fmaxf(acc[rt][ct][reg] + bv, 0.f));
      }
    }
  __syncthreads();
  #pragma unroll
  for (int i = 0; i < 8; i++) {
    int idx = t + 256 * i;
    int r = idx >> 4, c8 = idx & 15;
    if (row0 + r < nrows) {
      u16x8 v = *(const u16x8*)&As[r * 136 + c8 * 8];
      *(u16x8*)(Yh + (size_t)(row0 + r) * 128 + c8 * 8) = v;
      *(u16x8*)(Y2h + (size_t)(row0 + r) * 128 + c8 * 8) = v;
    }
  }
}

// ---------------- output GEMM: out[nrows,40] = Xh @ Wout + bout ----------------

__global__ __launch_bounds__(256) void gemm_out(const u16* __restrict__ Xh,
                                                const float* __restrict__ W,
                                                const float* __restrict__ bias,
                                                float* __restrict__ Y, int nrows) {
  __shared__ float xs[128][36];
  __shared__ float ws[32][44];
  int t = threadIdx.x;
  int tr = t >> 3;
  int tc = t & 7;
  int row0 = blockIdx.x * 128;
  float acc[4][5];
  #pragma unroll
  for (int i = 0; i < 4; i++)
    #pragma unroll
    for (int j = 0; j < 5; j++) acc[i][j] = 0.f;

  for (int k0 = 0; k0 < 128; k0 += 32) {
    #pragma unroll
    for (int i = 0; i < 2; i++) {
      int idx = t + 256 * i;
      int r = idx >> 2, c8 = idx & 3;
      int gr = row0 + r;
      u16x8 v = {0, 0, 0, 0, 0, 0, 0, 0};
      if (gr < nrows) v = *(const u16x8*)(Xh + (size_t)gr * 128 + k0 + c8 * 8);
      #pragma unroll
      for (int q = 0; q < 8; q++) xs[r][c8 * 8 + q] = bf2f(v[q]);
    }
    #pragma unroll
    for (int i = 0; i < 5; i++) {
      int idx = t + 256 * i;
      int r = idx / 40, c = idx % 40;
      ws[r][c] = W[(k0 + r) * 40 + c];
    }
    __syncthreads();
    #pragma unroll
    for (int kk4 = 0; kk4 < 8; kk4++) {
      float4 xv[4];
      #pragma unroll
      for (int i = 0; i < 4; i++) xv[i] = *(const float4*)&xs[tr + 32 * i][kk4 * 4];
      #pragma unroll
      for (int q = 0; q < 4; q++) {
        int kk = kk4 * 4 + q;
        float wv[5];
        #pragma unroll
        for (int j = 0; j < 5; j++) wv[j] = ws[kk][tc * 5 + j];
        #pragma unroll
        for (int i = 0; i < 4; i++) {
          float xq = ((const float*)&xv[i])[q];
          #pragma unroll
          for (int j = 0; j < 5; j++) acc[i][j] += xq * wv[j];
        }
      }
    }
    __syncthreads();
  }
  #pragma unroll
  for (int i = 0; i < 4; i++) {
    int gr = row0 + tr + 32 * i;
    if (gr >= nrows) continue;
    #pragma unroll
    for (int j = 0; j < 5; j++) {
      int c = tc * 5 + j;
      Y[(long)gr * 40 + c] = acc[i][j] + bias[c];
    }
  }
}

// ---------------- launch ----------------

extern "C" void kernel_launch(void* const* d_in, const int* in_sizes, int n_in,
                              void* d_out, int out_size, void* d_ws, size_t ws_size,
                              hipStream_t stream) {
  const float* x    = (const float*)d_in[0];
  const float* W0   = (const float*)d_in[1];
  const float* b0   = (const float*)d_in[2];
  const float* Ws   = (const float*)d_in[3];
  const float* Wout = (const float*)d_in[4];
  const float* bout = (const float*)d_in[5];
  const int* vertex = (const int*)d_in[6];
  const int* edges  = (const int*)d_in[7];
  float* out = (float*)d_out;

  char* base = (char*)d_ws;
  size_t o = 0;
  auto alloc = [&](size_t bytes) -> char* {
    char* r = base + o;
    o += (bytes + 255) & ~(size_t)255;
    return r;
  };
  u16* x_curh = (u16*)alloc((size_t)(NV + 1) * 128 * 2);  // +1 dummy zero row
  u16* x0h    = (u16*)alloc((size_t)NV * 128 * 2);
  u16* Xeh    = (u16*)alloc((size_t)(NE + 1) * 128 * 2);  // +1 dummy zero row
  u16* WT     = (u16*)alloc((size_t)5 * 16384 * 2);
  int* cntE   = (int*)alloc((size_t)NE * 4);
  int* cntV   = (int*)alloc((size_t)NV * 4);
  int* itemsE = (int*)alloc((size_t)NE * CAP_E * 4);
  int* itemsV = (int*)alloc((size_t)NV * CAP_V * 4);
  uint32* pairE = (uint32*)alloc((size_t)NB_E * CAPB_E * 4);
  uint32* pairV = (uint32*)alloc((size_t)NB_V * CAPB_V * 4);
  uint2* ovfE  = (uint2*)alloc((size_t)OVF_CAP * 8);
  uint2* ovfV  = (uint2*)alloc((size_t)OVF_CAP * 8);
  int* curAll = (int*)alloc((size_t)(NB_E + NB_V + 2) * 4);  // curE | curV | ovfCnt[2]
  int* curE = curAll;
  int* curV = curAll + NB_E;
  int* ovfCnt = curAll + NB_E + NB_V;

  int nzero = NB_E + NB_V + 2;
  zero_misc<<<(nzero + 255) / 256, 256, 0, stream>>>(curAll, nzero,
                                                     x_curh + (size_t)NV * 128,
                                                     Xeh + (size_t)NE * 128);
  scatter_binned<<<N_TILES, 256, 0, stream>>>(vertex, edges, curE, curV, ovfCnt,
                                              pairE, pairV, ovfE, ovfV);
  expand<<<NB_E, 256, 0, stream>>>(pairE, curE, CAPB_E, ovfE, ovfCnt,
                                   itemsE, CAP_E, cntE, NE, 16, NV);
  expand<<<NB_V, 256, 0, stream>>>(pairV, curV, CAPB_V, ovfV, ovfCnt + 1,
                                   itemsV, CAP_V, cntV, NV, 8, NE);
  prep_weights<<<(5 * 16384 + 255) / 256, 256, 0, stream>>>(W0, Ws, WT);

  int gblocks = (NV + 127) / 128;
  int fblocks = (NV + 31) / 32;
  gemm_first<<<gblocks, 256, 0, stream>>>(x, WT, b0, x_curh, x0h, NV);

  for (int i = 0; i < 4; i++) {
    edge_agg<<<NE / 16, 256, 0, stream>>>(x_curh, cntE, itemsE, Xeh);
    gemm_fused<<<fblocks, 256, 0, stream>>>(Xeh, cntV, itemsV, x0h,
                                            WT + (size_t)(1 + i) * 16384, x_curh, NV);
  }
  gemm_out<<<gblocks, 256, 0, stream>>>(x_curh, Wout, bout, out, NV);
}